// Round 3
// baseline (395.530 us; speedup 1.0000x reference)
//
#include <hip/hip_runtime.h>
#include <hip/hip_bf16.h>

typedef __attribute__((ext_vector_type(8))) short short8;
typedef __attribute__((ext_vector_type(4))) float f32x4;
typedef __hip_bfloat16 bf16;

#define NH 16
#define DK 64
#define SEQ 2048
#define DIM 1024
#define NEG_INF_F (-1.0e9f)

static __device__ __forceinline__ unsigned short f2bf_bits(float f) {
    bf16 t = __float2bfloat16(f);
    return *reinterpret_cast<unsigned short*>(&t);
}

// ---------------- convert f32 -> bf16, vectorized x4 ----------------
__global__ void cvt_kernel(const float* __restrict__ in, bf16* __restrict__ out, int n4) {
    int i = blockIdx.x * blockDim.x + threadIdx.x;
    if (i >= n4) return;
    float4 v = reinterpret_cast<const float4*>(in)[i];
    ushort4 u;
    u.x = f2bf_bits(v.x);
    u.y = f2bf_bits(v.y);
    u.z = f2bf_bits(v.z);
    u.w = f2bf_bits(v.w);
    reinterpret_cast<ushort4*>(out)[i] = u;
}

// ---------------- W (K x N) f32 -> Wt (N x K) bf16, LDS tiled ----------------
__global__ void transpose_cvt_kernel(const float* __restrict__ W, bf16* __restrict__ Wt) {
    __shared__ float t[32][33];
    int n0 = blockIdx.x * 32, k0 = blockIdx.y * 32;
    int tx = threadIdx.x, ty = threadIdx.y;   // 32 x 8
#pragma unroll
    for (int i = 0; i < 4; i++)
        t[ty + i * 8][tx] = W[(size_t)(k0 + ty + i * 8) * DIM + n0 + tx];
    __syncthreads();
#pragma unroll
    for (int i = 0; i < 4; i++)
        Wt[(size_t)(n0 + ty + i * 8) * DIM + k0 + tx] = __float2bfloat16(t[tx][ty + i * 8]);
}

// ---------------- bf16 MFMA GEMM: C = X(4096x1024) * Wt(1024x1024)^T + bias ----------------
// mode 0: Q -> head layout (B,H,S,DK) bf16, scaled by 1/8
// mode 1: K -> head layout (B,H,S,DK) bf16
// mode 2: V -> transposed head layout (B,H,DK,S) bf16
// mode 3: O -> f32 (B*S, D) to d_out
__global__ __launch_bounds__(256) void gemm_kernel(
    const bf16* __restrict__ X, const bf16* __restrict__ Wt,
    const float* __restrict__ bias, void* __restrict__ out, int mode)
{
    __shared__ __align__(16) bf16 Xs[128 * 40];   // pad 32 -> 40 elements
    __shared__ __align__(16) bf16 Ws[128 * 40];
    const int tid = threadIdx.x;
    const int w = tid >> 6, l = tid & 63;
    const int l15 = l & 15, l4 = l >> 4;
    const int m0 = blockIdx.x * 128, n0 = blockIdx.y * 128;
    const int wr = w >> 1, wc = w & 1;
    const int K = 1024;
    f32x4 acc[4][4] = {};

    for (int k0 = 0; k0 < K; k0 += 32) {
#pragma unroll
        for (int jj = 0; jj < 2; jj++) {
            int c = jj * 256 + tid;          // 512 16B-chunks per 128x32 tile
            int r = c >> 2, ch = c & 3;      // 32 elems/row = 4 x 16B chunks
            *reinterpret_cast<short8*>(&Xs[r * 40 + ch * 8]) =
                *reinterpret_cast<const short8*>(&X[(size_t)(m0 + r) * K + k0 + ch * 8]);
            *reinterpret_cast<short8*>(&Ws[r * 40 + ch * 8]) =
                *reinterpret_cast<const short8*>(&Wt[(size_t)(n0 + r) * K + k0 + ch * 8]);
        }
        __syncthreads();
        short8 af[4], bfr[4];
#pragma unroll
        for (int mi = 0; mi < 4; mi++)
            af[mi] = *reinterpret_cast<const short8*>(&Xs[(wr * 64 + mi * 16 + l15) * 40 + l4 * 8]);
#pragma unroll
        for (int ni = 0; ni < 4; ni++)
            bfr[ni] = *reinterpret_cast<const short8*>(&Ws[(wc * 64 + ni * 16 + l15) * 40 + l4 * 8]);
#pragma unroll
        for (int mi = 0; mi < 4; mi++)
#pragma unroll
            for (int ni = 0; ni < 4; ni++)
                acc[mi][ni] = __builtin_amdgcn_mfma_f32_16x16x32_bf16(af[mi], bfr[ni], acc[mi][ni], 0, 0, 0);
        __syncthreads();
    }

#pragma unroll
    for (int mi = 0; mi < 4; mi++) {
#pragma unroll
        for (int ni = 0; ni < 4; ni++) {
            int n = n0 + wc * 64 + ni * 16 + l15;
            float bv = bias[n];
#pragma unroll
            for (int j = 0; j < 4; j++) {
                int m = m0 + wr * 64 + mi * 16 + l4 * 4 + j;
                float val = acc[mi][ni][j] + bv;
                int b = m >> 11, s = m & 2047;
                int h = n >> 6, d = n & 63;
                if (mode == 0)
                    ((bf16*)out)[((size_t)(b * NH + h) * SEQ + s) * DK + d] = __float2bfloat16(val * 0.125f);
                else if (mode == 1)
                    ((bf16*)out)[((size_t)(b * NH + h) * SEQ + s) * DK + d] = __float2bfloat16(val);
                else if (mode == 2)
                    ((bf16*)out)[((size_t)(b * NH + h) * DK + d) * SEQ + s] = __float2bfloat16(val);
                else
                    ((float*)out)[(size_t)m * DIM + n] = val;
            }
        }
    }
}

// ---------------- fused flash attention + scores materialization ----------------
// grid: (16 q-tiles, 32 b*h). block: 256 threads = 4 waves, each wave owns 32 q-rows.
// KVBLK = 64: matches sacc[2][4] coverage (64 kv cols) exactly.
__global__ __launch_bounds__(256) void attn_kernel(
    const bf16* __restrict__ Qh, const bf16* __restrict__ Kh,
    const bf16* __restrict__ Vt, const int* __restrict__ mask,
    float* __restrict__ scores, bf16* __restrict__ attn_c)
{
    __shared__ __align__(16) bf16 Ks[64 * 72];    // K tile 64x64, padded stride 72
    __shared__ __align__(16) bf16 Vs[64 * 72];    // V^T tile 64(dk) x 64(kv), stride 72
    __shared__ __align__(16) bf16 Ps[128 * 72];   // P tile 128x64, stride 72
    const int tid = threadIdx.x;
    const int w = tid >> 6, l = tid & 63;
    const int l15 = l & 15, l4 = l >> 4;
    const int bh = blockIdx.y;
    const int b = bh >> 4, h = bh & 15;
    const int q0 = blockIdx.x * 128;
    const size_t head = (size_t)bh * SEQ * DK;

    // Q fragments direct from global (Qh already scaled by 1/8)
    short8 aq[2][2];
#pragma unroll
    for (int mi = 0; mi < 2; mi++)
#pragma unroll
        for (int ks = 0; ks < 2; ks++)
            aq[mi][ks] = *reinterpret_cast<const short8*>(
                &Qh[head + (size_t)(q0 + w * 32 + mi * 16 + l15) * DK + ks * 32 + l4 * 8]);

    f32x4 oacc[2][4] = {};
    float mrun[2][4], lrun[2][4];
#pragma unroll
    for (int mi = 0; mi < 2; mi++)
#pragma unroll
        for (int j = 0; j < 4; j++) { mrun[mi][j] = -INFINITY; lrun[mi][j] = 0.f; }

    for (int kv0 = 0; kv0 < SEQ; kv0 += 64) {
        // stage K (64x64) and V^T (64x64): 512 16B-chunks each, 8 chunks per 64-elem row
#pragma unroll
        for (int jj = 0; jj < 2; jj++) {
            int c = jj * 256 + tid;           // [0,512)
            int r = c >> 3, ch = c & 7;       // 64 elems/row = 128B = 8 x 16B chunks
            *reinterpret_cast<short8*>(&Ks[r * 72 + ch * 8]) =
                *reinterpret_cast<const short8*>(&Kh[head + (size_t)(kv0 + r) * DK + ch * 8]);
            *reinterpret_cast<short8*>(&Vs[r * 72 + ch * 8]) =
                *reinterpret_cast<const short8*>(&Vt[head + (size_t)r * SEQ + kv0 + ch * 8]);
        }
        __syncthreads();

        // S = Q * K^T (scale already folded into Q); 32 q-rows x 64 kv-cols per wave
        f32x4 sacc[2][4] = {};
#pragma unroll
        for (int ks = 0; ks < 2; ks++) {
            short8 bk[4];
#pragma unroll
            for (int ni = 0; ni < 4; ni++)
                bk[ni] = *reinterpret_cast<const short8*>(&Ks[(ni * 16 + l15) * 72 + ks * 32 + l4 * 8]);
#pragma unroll
            for (int mi = 0; mi < 2; mi++)
#pragma unroll
                for (int ni = 0; ni < 4; ni++)
                    sacc[mi][ni] = __builtin_amdgcn_mfma_f32_16x16x32_bf16(aq[mi][ks], bk[ni], sacc[mi][ni], 0, 0, 0);
        }

        // mask
        int mk[4];
#pragma unroll
        for (int ni = 0; ni < 4; ni++) mk[ni] = mask[b * SEQ + kv0 + ni * 16 + l15];
#pragma unroll
        for (int mi = 0; mi < 2; mi++)
#pragma unroll
            for (int ni = 0; ni < 4; ni++)
                if (mk[ni] == 0) {
#pragma unroll
                    for (int j = 0; j < 4; j++) sacc[mi][ni][j] = NEG_INF_F;
                }

        // write masked raw scores (output 1)
        {
            size_t base = ((size_t)bh * SEQ + q0 + w * 32) * SEQ + kv0;
#pragma unroll
            for (int mi = 0; mi < 2; mi++)
#pragma unroll
                for (int j = 0; j < 4; j++) {
                    size_t rb = base + (size_t)(mi * 16 + l4 * 4 + j) * SEQ;
#pragma unroll
                    for (int ni = 0; ni < 4; ni++)
                        scores[rb + ni * 16 + l15] = sacc[mi][ni][j];
                }
        }

        // online softmax per q-row (each 16-lane group owns its rows)
#pragma unroll
        for (int mi = 0; mi < 2; mi++)
#pragma unroll
            for (int j = 0; j < 4; j++) {
                float mx = fmaxf(fmaxf(sacc[mi][0][j], sacc[mi][1][j]),
                                 fmaxf(sacc[mi][2][j], sacc[mi][3][j]));
#pragma unroll
                for (int d = 1; d < 16; d <<= 1) mx = fmaxf(mx, __shfl_xor(mx, d));
                float mnew = fmaxf(mrun[mi][j], mx);
                float fac = __expf(mrun[mi][j] - mnew);
                float rs = 0.f;
#pragma unroll
                for (int ni = 0; ni < 4; ni++) {
                    float p = __expf(sacc[mi][ni][j] - mnew);
                    sacc[mi][ni][j] = p;
                    rs += p;
                }
#pragma unroll
                for (int d = 1; d < 16; d <<= 1) rs += __shfl_xor(rs, d);
                lrun[mi][j] = lrun[mi][j] * fac + rs;
                mrun[mi][j] = mnew;
#pragma unroll
                for (int ni = 0; ni < 4; ni++) oacc[mi][ni][j] *= fac;
            }

        // P -> LDS bf16 (each wave only touches its own 32 rows)
#pragma unroll
        for (int mi = 0; mi < 2; mi++)
#pragma unroll
            for (int j = 0; j < 4; j++) {
                int r = w * 32 + mi * 16 + l4 * 4 + j;
#pragma unroll
                for (int ni = 0; ni < 4; ni++)
                    Ps[r * 72 + ni * 16 + l15] = __float2bfloat16(sacc[mi][ni][j]);
            }

        // O += P * V   (kv = ks*32 + l4*8, covers 64)
#pragma unroll
        for (int ks = 0; ks < 2; ks++) {
            short8 pa[2], vbf[4];
#pragma unroll
            for (int mi = 0; mi < 2; mi++)
                pa[mi] = *reinterpret_cast<const short8*>(&Ps[(w * 32 + mi * 16 + l15) * 72 + ks * 32 + l4 * 8]);
#pragma unroll
            for (int ni = 0; ni < 4; ni++)
                vbf[ni] = *reinterpret_cast<const short8*>(&Vs[(ni * 16 + l15) * 72 + ks * 32 + l4 * 8]);
#pragma unroll
            for (int mi = 0; mi < 2; mi++)
#pragma unroll
                for (int ni = 0; ni < 4; ni++)
                    oacc[mi][ni] = __builtin_amdgcn_mfma_f32_16x16x32_bf16(pa[mi], vbf[ni], oacc[mi][ni], 0, 0, 0);
        }
        __syncthreads();
    }

    // epilogue: normalize and write concat layout (B, S, H*DK) bf16
#pragma unroll
    for (int mi = 0; mi < 2; mi++)
#pragma unroll
        for (int j = 0; j < 4; j++) {
            int s = q0 + w * 32 + mi * 16 + l4 * 4 + j;
            float inv = 1.f / lrun[mi][j];
#pragma unroll
            for (int ni = 0; ni < 4; ni++)
                attn_c[((size_t)(b * SEQ + s)) * DIM + h * DK + ni * 16 + l15] =
                    __float2bfloat16(oacc[mi][ni][j] * inv);
        }
}

extern "C" void kernel_launch(void* const* d_in, const int* in_sizes, int n_in,
                              void* d_out, int out_size, void* d_ws, size_t ws_size,
                              hipStream_t stream)
{
    const float* q  = (const float*)d_in[0];
    const float* k  = (const float*)d_in[1];
    const float* v  = (const float*)d_in[2];
    const int*  msk = (const int*)d_in[3];
    const float* Wq = (const float*)d_in[4];
    const float* bq = (const float*)d_in[5];
    const float* Wk = (const float*)d_in[6];
    const float* bk = (const float*)d_in[7];
    const float* Wv = (const float*)d_in[8];
    const float* bv = (const float*)d_in[9];
    const float* Wo = (const float*)d_in[10];
    const float* bo = (const float*)d_in[11];

    // workspace layout (bf16), 64 MB total
    const size_t MB = 1ull << 20;
    char* ws = (char*)d_ws;
    bf16* qb  = (bf16*)(ws + 0 * MB);
    bf16* kb  = (bf16*)(ws + 8 * MB);
    bf16* vb  = (bf16*)(ws + 16 * MB);
    bf16* Wqt = (bf16*)(ws + 24 * MB);
    bf16* Wkt = (bf16*)(ws + 26 * MB);
    bf16* Wvt = (bf16*)(ws + 28 * MB);
    bf16* Wot = (bf16*)(ws + 30 * MB);
    bf16* QhD = (bf16*)(ws + 32 * MB);   // (B,H,S,DK) scaled 1/8
    bf16* KhD = (bf16*)(ws + 40 * MB);   // (B,H,S,DK)
    bf16* VtD = (bf16*)(ws + 48 * MB);   // (B,H,DK,S)
    bf16* att = (bf16*)(ws + 56 * MB);   // (B,S,H*DK)

    float* out = (float*)d_out;
    float* scores = out + (size_t)4096 * 1024;

    int n4 = (2 * SEQ * DIM) / 4;        // 1,048,576
    cvt_kernel<<<n4 / 256, 256, 0, stream>>>(q, qb, n4);
    cvt_kernel<<<n4 / 256, 256, 0, stream>>>(k, kb, n4);
    cvt_kernel<<<n4 / 256, 256, 0, stream>>>(v, vb, n4);

    dim3 tg(32, 32), tb(32, 8);
    transpose_cvt_kernel<<<tg, tb, 0, stream>>>(Wq, Wqt);
    transpose_cvt_kernel<<<tg, tb, 0, stream>>>(Wk, Wkt);
    transpose_cvt_kernel<<<tg, tb, 0, stream>>>(Wv, Wvt);
    transpose_cvt_kernel<<<tg, tb, 0, stream>>>(Wo, Wot);

    dim3 gg(32, 8);
    gemm_kernel<<<gg, 256, 0, stream>>>(qb, Wqt, bq, QhD, 0);
    gemm_kernel<<<gg, 256, 0, stream>>>(kb, Wkt, bk, KhD, 1);
    gemm_kernel<<<gg, 256, 0, stream>>>(vb, Wvt, bv, VtD, 2);

    dim3 ag(16, 32);
    attn_kernel<<<ag, 256, 0, stream>>>(QhD, KhD, VtD, msk, scores, att);

    gemm_kernel<<<gg, 256, 0, stream>>>(att, Wot, bo, d_out, 3);
}

// Round 4
// 292.835 us; speedup vs baseline: 1.3507x; 1.3507x over previous
//
#include <hip/hip_runtime.h>
#include <hip/hip_bf16.h>

typedef __attribute__((ext_vector_type(8))) short short8;
typedef __attribute__((ext_vector_type(4))) float f32x4;
typedef __hip_bfloat16 bf16;

#define NH 16
#define DK 64
#define SEQ 2048
#define DIM 1024
#define NEG_INF_F (-1.0e9f)

static __device__ __forceinline__ unsigned short f2bf_bits(float f) {
    bf16 t = __float2bfloat16(f);
    return *reinterpret_cast<unsigned short*>(&t);
}

// ---------------- convert f32 -> bf16, vectorized x4 ----------------
__global__ void cvt_kernel(const float* __restrict__ in, bf16* __restrict__ out, int n4) {
    int i = blockIdx.x * blockDim.x + threadIdx.x;
    if (i >= n4) return;
    float4 v = reinterpret_cast<const float4*>(in)[i];
    ushort4 u;
    u.x = f2bf_bits(v.x);
    u.y = f2bf_bits(v.y);
    u.z = f2bf_bits(v.z);
    u.w = f2bf_bits(v.w);
    reinterpret_cast<ushort4*>(out)[i] = u;
}

// ---------------- W (K x N) f32 -> Wt (N x K) bf16, LDS tiled ----------------
__global__ void transpose_cvt_kernel(const float* __restrict__ W, bf16* __restrict__ Wt) {
    __shared__ float t[32][33];
    int n0 = blockIdx.x * 32, k0 = blockIdx.y * 32;
    int tx = threadIdx.x, ty = threadIdx.y;   // 32 x 8
#pragma unroll
    for (int i = 0; i < 4; i++)
        t[ty + i * 8][tx] = W[(size_t)(k0 + ty + i * 8) * DIM + n0 + tx];
    __syncthreads();
#pragma unroll
    for (int i = 0; i < 4; i++)
        Wt[(size_t)(n0 + ty + i * 8) * DIM + k0 + tx] = __float2bfloat16(t[tx][ty + i * 8]);
}

// ---------------- fused QKV projection GEMM ----------------
// grid (32, 24): by>>3 selects proj (0=Q,1=K,2=V); 128x128 tile, BK=32,
// reg-staged double-buffered LDS, ONE barrier per K-step.
__global__ __launch_bounds__(256) void qkv_gemm_kernel(
    const bf16* __restrict__ qb, const bf16* __restrict__ kb, const bf16* __restrict__ vb,
    const bf16* __restrict__ Wcat,   // [3*1024][1024] row-major (N-major, transposed)
    const float* __restrict__ bq, const float* __restrict__ bk, const float* __restrict__ bv,
    bf16* __restrict__ Qh, bf16* __restrict__ Kh, bf16* __restrict__ Vt)
{
    __shared__ __align__(16) bf16 Xs[2][128 * 40];
    __shared__ __align__(16) bf16 Ws[2][128 * 40];
    const int tid = threadIdx.x;
    const int w = tid >> 6, l = tid & 63;
    const int l15 = l & 15, l4 = l >> 4;
    const int m0 = blockIdx.x * 128;
    const int by = blockIdx.y;
    const int proj = by >> 3;
    const int n0 = (by & 7) * 128;
    const bf16* X = (proj == 0) ? qb : (proj == 1) ? kb : vb;
    const bf16* Wt = Wcat + (size_t)proj * DIM * DIM + (size_t)n0 * DIM;
    const float* bias = (proj == 0) ? bq : (proj == 1) ? bk : bv;
    const int wr = w >> 1, wc = w & 1;
    f32x4 acc[4][4] = {};

    // staging decode: 512 16B-chunks per 128x32 tile, 2 per thread
    const int c0 = tid, c1 = 256 + tid;
    const int r0 = c0 >> 2, ch0 = c0 & 3;
    const int r1 = c1 >> 2, ch1 = c1 & 3;
    const bf16* Xp = X + (size_t)m0 * DIM;

    // prologue: tile k0=0 -> buf 0
    short8 x0 = *reinterpret_cast<const short8*>(&Xp[(size_t)r0 * DIM + ch0 * 8]);
    short8 x1 = *reinterpret_cast<const short8*>(&Xp[(size_t)r1 * DIM + ch1 * 8]);
    short8 w0 = *reinterpret_cast<const short8*>(&Wt[(size_t)r0 * DIM + ch0 * 8]);
    short8 w1 = *reinterpret_cast<const short8*>(&Wt[(size_t)r1 * DIM + ch1 * 8]);
    *reinterpret_cast<short8*>(&Xs[0][r0 * 40 + ch0 * 8]) = x0;
    *reinterpret_cast<short8*>(&Xs[0][r1 * 40 + ch1 * 8]) = x1;
    *reinterpret_cast<short8*>(&Ws[0][r0 * 40 + ch0 * 8]) = w0;
    *reinterpret_cast<short8*>(&Ws[0][r1 * 40 + ch1 * 8]) = w1;
    __syncthreads();

    int cur = 0;
    for (int k0 = 0; k0 < DIM; k0 += 32) {
        const bool more = (k0 + 32) < DIM;
        short8 nx0, nx1, nw0, nw1;
        if (more) {   // issue next-tile loads early; they hide under MFMA
            nx0 = *reinterpret_cast<const short8*>(&Xp[(size_t)r0 * DIM + k0 + 32 + ch0 * 8]);
            nx1 = *reinterpret_cast<const short8*>(&Xp[(size_t)r1 * DIM + k0 + 32 + ch1 * 8]);
            nw0 = *reinterpret_cast<const short8*>(&Wt[(size_t)r0 * DIM + k0 + 32 + ch0 * 8]);
            nw1 = *reinterpret_cast<const short8*>(&Wt[(size_t)r1 * DIM + k0 + 32 + ch1 * 8]);
        }
        short8 af[4], bfr[4];
#pragma unroll
        for (int mi = 0; mi < 4; mi++)
            af[mi] = *reinterpret_cast<const short8*>(&Xs[cur][(wr * 64 + mi * 16 + l15) * 40 + l4 * 8]);
#pragma unroll
        for (int ni = 0; ni < 4; ni++)
            bfr[ni] = *reinterpret_cast<const short8*>(&Ws[cur][(wc * 64 + ni * 16 + l15) * 40 + l4 * 8]);
#pragma unroll
        for (int mi = 0; mi < 4; mi++)
#pragma unroll
            for (int ni = 0; ni < 4; ni++)
                acc[mi][ni] = __builtin_amdgcn_mfma_f32_16x16x32_bf16(af[mi], bfr[ni], acc[mi][ni], 0, 0, 0);
        if (more) {
            *reinterpret_cast<short8*>(&Xs[cur ^ 1][r0 * 40 + ch0 * 8]) = nx0;
            *reinterpret_cast<short8*>(&Xs[cur ^ 1][r1 * 40 + ch1 * 8]) = nx1;
            *reinterpret_cast<short8*>(&Ws[cur ^ 1][r0 * 40 + ch0 * 8]) = nw0;
            *reinterpret_cast<short8*>(&Ws[cur ^ 1][r1 * 40 + ch1 * 8]) = nw1;
        }
        __syncthreads();
        cur ^= 1;
    }

#pragma unroll
    for (int mi = 0; mi < 4; mi++) {
#pragma unroll
        for (int ni = 0; ni < 4; ni++) {
            int n = n0 + wc * 64 + ni * 16 + l15;   // within this proj's 1024
            float bv = bias[n];
            int h = n >> 6, d = n & 63;
#pragma unroll
            for (int j = 0; j < 4; j++) {
                int m = m0 + wr * 64 + mi * 16 + l4 * 4 + j;
                float val = acc[mi][ni][j] + bv;
                int b = m >> 11, s = m & 2047;
                if (proj == 0)
                    Qh[((size_t)(b * NH + h) * SEQ + s) * DK + d] = __float2bfloat16(val * 0.125f);
                else if (proj == 1)
                    Kh[((size_t)(b * NH + h) * SEQ + s) * DK + d] = __float2bfloat16(val);
                else
                    Vt[((size_t)(b * NH + h) * DK + d) * SEQ + s] = __float2bfloat16(val);
            }
        }
    }
}

// ---------------- O projection GEMM: out(4096x1024 f32) = att * Wot^T + bo ----------------
// 64x128 tile (grid 64x8 = 512 blocks -> 2/CU), double-buffered, one barrier/K-step.
__global__ __launch_bounds__(256) void o_gemm_kernel(
    const bf16* __restrict__ X, const bf16* __restrict__ Wt,
    const float* __restrict__ bias, float* __restrict__ out)
{
    __shared__ __align__(16) bf16 Xs[2][64 * 40];
    __shared__ __align__(16) bf16 Ws[2][128 * 40];
    const int tid = threadIdx.x;
    const int w = tid >> 6, l = tid & 63;
    const int l15 = l & 15, l4 = l >> 4;
    const int m0 = blockIdx.x * 64, n0 = blockIdx.y * 128;
    const int wr = w >> 1, wc = w & 1;
    f32x4 acc[2][4] = {};

    // X tile 64x32: 256 chunks, 1/thread. W tile 128x32: 512 chunks, 2/thread.
    const int xr = tid >> 2, xc = tid & 3;
    const int c0 = tid, c1 = 256 + tid;
    const int wr0 = c0 >> 2, wc0 = c0 & 3;
    const int wr1 = c1 >> 2, wc1 = c1 & 3;
    const bf16* Xp = X + (size_t)m0 * DIM;
    const bf16* Wp = Wt + (size_t)n0 * DIM;

    short8 x0 = *reinterpret_cast<const short8*>(&Xp[(size_t)xr * DIM + xc * 8]);
    short8 w0 = *reinterpret_cast<const short8*>(&Wp[(size_t)wr0 * DIM + wc0 * 8]);
    short8 w1 = *reinterpret_cast<const short8*>(&Wp[(size_t)wr1 * DIM + wc1 * 8]);
    *reinterpret_cast<short8*>(&Xs[0][xr * 40 + xc * 8]) = x0;
    *reinterpret_cast<short8*>(&Ws[0][wr0 * 40 + wc0 * 8]) = w0;
    *reinterpret_cast<short8*>(&Ws[0][wr1 * 40 + wc1 * 8]) = w1;
    __syncthreads();

    int cur = 0;
    for (int k0 = 0; k0 < DIM; k0 += 32) {
        const bool more = (k0 + 32) < DIM;
        short8 nx0, nw0, nw1;
        if (more) {
            nx0 = *reinterpret_cast<const short8*>(&Xp[(size_t)xr * DIM + k0 + 32 + xc * 8]);
            nw0 = *reinterpret_cast<const short8*>(&Wp[(size_t)wr0 * DIM + k0 + 32 + wc0 * 8]);
            nw1 = *reinterpret_cast<const short8*>(&Wp[(size_t)wr1 * DIM + k0 + 32 + wc1 * 8]);
        }
        short8 af[2], bfr[4];
#pragma unroll
        for (int mi = 0; mi < 2; mi++)
            af[mi] = *reinterpret_cast<const short8*>(&Xs[cur][(wr * 32 + mi * 16 + l15) * 40 + l4 * 8]);
#pragma unroll
        for (int ni = 0; ni < 4; ni++)
            bfr[ni] = *reinterpret_cast<const short8*>(&Ws[cur][(wc * 64 + ni * 16 + l15) * 40 + l4 * 8]);
#pragma unroll
        for (int mi = 0; mi < 2; mi++)
#pragma unroll
            for (int ni = 0; ni < 4; ni++)
                acc[mi][ni] = __builtin_amdgcn_mfma_f32_16x16x32_bf16(af[mi], bfr[ni], acc[mi][ni], 0, 0, 0);
        if (more) {
            *reinterpret_cast<short8*>(&Xs[cur ^ 1][xr * 40 + xc * 8]) = nx0;
            *reinterpret_cast<short8*>(&Ws[cur ^ 1][wr0 * 40 + wc0 * 8]) = nw0;
            *reinterpret_cast<short8*>(&Ws[cur ^ 1][wr1 * 40 + wc1 * 8]) = nw1;
        }
        __syncthreads();
        cur ^= 1;
    }

#pragma unroll
    for (int mi = 0; mi < 2; mi++) {
#pragma unroll
        for (int ni = 0; ni < 4; ni++) {
            int n = n0 + wc * 64 + ni * 16 + l15;
            float bv = bias[n];
#pragma unroll
            for (int j = 0; j < 4; j++) {
                int m = m0 + wr * 32 + mi * 16 + l4 * 4 + j;
                out[(size_t)m * DIM + n] = acc[mi][ni][j] + bv;
            }
        }
    }
}

// ---------------- fused flash attention + scores materialization ----------------
// grid (16, 32), 256 threads = 4 waves, 32 q-rows/wave, KVBLK=64.
// Double-buffered K/V staging, one barrier per kv-step, mask preloaded to LDS.
__global__ __launch_bounds__(256) void attn_kernel(
    const bf16* __restrict__ Qh, const bf16* __restrict__ Kh,
    const bf16* __restrict__ Vt, const int* __restrict__ mask,
    float* __restrict__ scores, bf16* __restrict__ attn_c)
{
    __shared__ __align__(16) bf16 Ks[2][64 * 72];
    __shared__ __align__(16) bf16 Vs[2][64 * 72];
    __shared__ __align__(16) bf16 Ps[128 * 72];
    __shared__ int msk_s[SEQ];
    const int tid = threadIdx.x;
    const int w = tid >> 6, l = tid & 63;
    const int l15 = l & 15, l4 = l >> 4;
    const int bh = blockIdx.y;
    const int b = bh >> 4, h = bh & 15;
    const int q0 = blockIdx.x * 128;
    const size_t head = (size_t)bh * SEQ * DK;

    // staging decode: 512 chunks per 64x64 tile, 2/thread (8 chunks per 128B row)
    const int c0 = tid, c1 = 256 + tid;
    const int kr0 = c0 >> 3, kc0 = c0 & 7;
    const int kr1 = c1 >> 3, kc1 = c1 & 7;

    // Q fragments direct from global (pre-scaled by 1/8)
    short8 aq[2][2];
#pragma unroll
    for (int mi = 0; mi < 2; mi++)
#pragma unroll
        for (int ks = 0; ks < 2; ks++)
            aq[mi][ks] = *reinterpret_cast<const short8*>(
                &Qh[head + (size_t)(q0 + w * 32 + mi * 16 + l15) * DK + ks * 32 + l4 * 8]);

    // preload mask row + kv tile 0
    {
        const int4* msrc = reinterpret_cast<const int4*>(mask + b * SEQ);
#pragma unroll
        for (int i = 0; i < 2; i++)
            reinterpret_cast<int4*>(msk_s)[i * 256 + tid] = msrc[i * 256 + tid];
        short8 k0v = *reinterpret_cast<const short8*>(&Kh[head + (size_t)kr0 * DK + kc0 * 8]);
        short8 k1v = *reinterpret_cast<const short8*>(&Kh[head + (size_t)kr1 * DK + kc1 * 8]);
        short8 v0v = *reinterpret_cast<const short8*>(&Vt[head + (size_t)kr0 * SEQ + kc0 * 8]);
        short8 v1v = *reinterpret_cast<const short8*>(&Vt[head + (size_t)kr1 * SEQ + kc1 * 8]);
        *reinterpret_cast<short8*>(&Ks[0][kr0 * 72 + kc0 * 8]) = k0v;
        *reinterpret_cast<short8*>(&Ks[0][kr1 * 72 + kc1 * 8]) = k1v;
        *reinterpret_cast<short8*>(&Vs[0][kr0 * 72 + kc0 * 8]) = v0v;
        *reinterpret_cast<short8*>(&Vs[0][kr1 * 72 + kc1 * 8]) = v1v;
    }
    __syncthreads();

    f32x4 oacc[2][4] = {};
    float mrun[2][4], lrun[2][4];
#pragma unroll
    for (int mi = 0; mi < 2; mi++)
#pragma unroll
        for (int j = 0; j < 4; j++) { mrun[mi][j] = -INFINITY; lrun[mi][j] = 0.f; }

    int cur = 0;
    for (int t = 0; t < SEQ / 64; t++) {
        const int kv0 = t * 64;
        const bool more = t < (SEQ / 64 - 1);
        short8 nk0, nk1, nv0, nv1;
        if (more) {   // issue next-tile loads; hide under QK^T + softmax + PV
            nk0 = *reinterpret_cast<const short8*>(&Kh[head + (size_t)(kv0 + 64 + kr0) * DK + kc0 * 8]);
            nk1 = *reinterpret_cast<const short8*>(&Kh[head + (size_t)(kv0 + 64 + kr1) * DK + kc1 * 8]);
            nv0 = *reinterpret_cast<const short8*>(&Vt[head + (size_t)kr0 * SEQ + kv0 + 64 + kc0 * 8]);
            nv1 = *reinterpret_cast<const short8*>(&Vt[head + (size_t)kr1 * SEQ + kv0 + 64 + kc1 * 8]);
        }

        // S = Q * K^T
        f32x4 sacc[2][4] = {};
#pragma unroll
        for (int ks = 0; ks < 2; ks++) {
            short8 bk[4];
#pragma unroll
            for (int ni = 0; ni < 4; ni++)
                bk[ni] = *reinterpret_cast<const short8*>(&Ks[cur][(ni * 16 + l15) * 72 + ks * 32 + l4 * 8]);
#pragma unroll
            for (int mi = 0; mi < 2; mi++)
#pragma unroll
                for (int ni = 0; ni < 4; ni++)
                    sacc[mi][ni] = __builtin_amdgcn_mfma_f32_16x16x32_bf16(aq[mi][ks], bk[ni], sacc[mi][ni], 0, 0, 0);
        }

        // mask (from LDS)
        int mk[4];
#pragma unroll
        for (int ni = 0; ni < 4; ni++) mk[ni] = msk_s[kv0 + ni * 16 + l15];
#pragma unroll
        for (int mi = 0; mi < 2; mi++)
#pragma unroll
            for (int ni = 0; ni < 4; ni++)
                if (mk[ni] == 0) {
#pragma unroll
                    for (int j = 0; j < 4; j++) sacc[mi][ni][j] = NEG_INF_F;
                }

        // write masked raw scores (output 1)
        {
            size_t base = ((size_t)bh * SEQ + q0 + w * 32) * SEQ + kv0;
#pragma unroll
            for (int mi = 0; mi < 2; mi++)
#pragma unroll
                for (int j = 0; j < 4; j++) {
                    size_t rb = base + (size_t)(mi * 16 + l4 * 4 + j) * SEQ;
#pragma unroll
                    for (int ni = 0; ni < 4; ni++)
                        scores[rb + ni * 16 + l15] = sacc[mi][ni][j];
                }
        }

        // online softmax per q-row; rescale only when the max grows
#pragma unroll
        for (int mi = 0; mi < 2; mi++)
#pragma unroll
            for (int j = 0; j < 4; j++) {
                float mx = fmaxf(fmaxf(sacc[mi][0][j], sacc[mi][1][j]),
                                 fmaxf(sacc[mi][2][j], sacc[mi][3][j]));
#pragma unroll
                for (int d = 1; d < 16; d <<= 1) mx = fmaxf(mx, __shfl_xor(mx, d));
                if (mx > mrun[mi][j]) {
                    float fac = __expf(mrun[mi][j] - mx);
                    lrun[mi][j] *= fac;
#pragma unroll
                    for (int ni = 0; ni < 4; ni++) oacc[mi][ni][j] *= fac;
                    mrun[mi][j] = mx;
                }
                float mcur = mrun[mi][j];
                float rs = 0.f;
#pragma unroll
                for (int ni = 0; ni < 4; ni++) {
                    float p = __expf(sacc[mi][ni][j] - mcur);
                    sacc[mi][ni][j] = p;
                    rs += p;
                }
#pragma unroll
                for (int d = 1; d < 16; d <<= 1) rs += __shfl_xor(rs, d);
                lrun[mi][j] += rs;
            }

        // P -> LDS (wave-local rows: no barrier needed)
#pragma unroll
        for (int mi = 0; mi < 2; mi++)
#pragma unroll
            for (int j = 0; j < 4; j++) {
                int r = w * 32 + mi * 16 + l4 * 4 + j;
#pragma unroll
                for (int ni = 0; ni < 4; ni++)
                    Ps[r * 72 + ni * 16 + l15] = __float2bfloat16(sacc[mi][ni][j]);
            }

        // O += P * V
#pragma unroll
        for (int ks = 0; ks < 2; ks++) {
            short8 pa[2], vbf[4];
#pragma unroll
            for (int mi = 0; mi < 2; mi++)
                pa[mi] = *reinterpret_cast<const short8*>(&Ps[(w * 32 + mi * 16 + l15) * 72 + ks * 32 + l4 * 8]);
#pragma unroll
            for (int ni = 0; ni < 4; ni++)
                vbf[ni] = *reinterpret_cast<const short8*>(&Vs[cur][(ni * 16 + l15) * 72 + ks * 32 + l4 * 8]);
#pragma unroll
            for (int mi = 0; mi < 2; mi++)
#pragma unroll
                for (int ni = 0; ni < 4; ni++)
                    oacc[mi][ni] = __builtin_amdgcn_mfma_f32_16x16x32_bf16(pa[mi], vbf[ni], oacc[mi][ni], 0, 0, 0);
        }

        if (more) {
            *reinterpret_cast<short8*>(&Ks[cur ^ 1][kr0 * 72 + kc0 * 8]) = nk0;
            *reinterpret_cast<short8*>(&Ks[cur ^ 1][kr1 * 72 + kc1 * 8]) = nk1;
            *reinterpret_cast<short8*>(&Vs[cur ^ 1][kr0 * 72 + kc0 * 8]) = nv0;
            *reinterpret_cast<short8*>(&Vs[cur ^ 1][kr1 * 72 + kc1 * 8]) = nv1;
        }
        __syncthreads();
        cur ^= 1;
    }

    // epilogue: normalize and write concat layout (B, S, H*DK) bf16
#pragma unroll
    for (int mi = 0; mi < 2; mi++)
#pragma unroll
        for (int j = 0; j < 4; j++) {
            int s = q0 + w * 32 + mi * 16 + l4 * 4 + j;
            float inv = 1.f / lrun[mi][j];
#pragma unroll
            for (int ni = 0; ni < 4; ni++)
                attn_c[((size_t)(b * SEQ + s)) * DIM + h * DK + ni * 16 + l15] =
                    __float2bfloat16(oacc[mi][ni][j] * inv);
        }
}

extern "C" void kernel_launch(void* const* d_in, const int* in_sizes, int n_in,
                              void* d_out, int out_size, void* d_ws, size_t ws_size,
                              hipStream_t stream)
{
    const float* q  = (const float*)d_in[0];
    const float* k  = (const float*)d_in[1];
    const float* v  = (const float*)d_in[2];
    const int*  msk = (const int*)d_in[3];
    const float* Wq = (const float*)d_in[4];
    const float* bq = (const float*)d_in[5];
    const float* Wk = (const float*)d_in[6];
    const float* bk = (const float*)d_in[7];
    const float* Wv = (const float*)d_in[8];
    const float* bv = (const float*)d_in[9];
    const float* Wo = (const float*)d_in[10];
    const float* bo = (const float*)d_in[11];

    const size_t MB = 1ull << 20;
    char* ws = (char*)d_ws;
    bf16* qb  = (bf16*)(ws + 0 * MB);
    bf16* kb  = (bf16*)(ws + 8 * MB);
    bf16* vb  = (bf16*)(ws + 16 * MB);
    bf16* Wqt = (bf16*)(ws + 24 * MB);   // Wq^T,Wk^T,Wv^T contiguous -> Wcat
    bf16* Wkt = (bf16*)(ws + 26 * MB);
    bf16* Wvt = (bf16*)(ws + 28 * MB);
    bf16* Wot = (bf16*)(ws + 30 * MB);
    bf16* QhD = (bf16*)(ws + 32 * MB);   // (B,H,S,DK) scaled 1/8
    bf16* KhD = (bf16*)(ws + 40 * MB);   // (B,H,S,DK)
    bf16* VtD = (bf16*)(ws + 48 * MB);   // (B,H,DK,S)
    bf16* att = (bf16*)(ws + 56 * MB);   // (B,S,H*DK)

    float* out = (float*)d_out;
    float* scores = out + (size_t)4096 * 1024;

    int n4 = (2 * SEQ * DIM) / 4;
    cvt_kernel<<<n4 / 256, 256, 0, stream>>>(q, qb, n4);
    cvt_kernel<<<n4 / 256, 256, 0, stream>>>(k, kb, n4);
    cvt_kernel<<<n4 / 256, 256, 0, stream>>>(v, vb, n4);

    dim3 tg(32, 32), tb(32, 8);
    transpose_cvt_kernel<<<tg, tb, 0, stream>>>(Wq, Wqt);
    transpose_cvt_kernel<<<tg, tb, 0, stream>>>(Wk, Wkt);
    transpose_cvt_kernel<<<tg, tb, 0, stream>>>(Wv, Wvt);
    transpose_cvt_kernel<<<tg, tb, 0, stream>>>(Wo, Wot);

    qkv_gemm_kernel<<<dim3(32, 24), 256, 0, stream>>>(qb, kb, vb, Wqt, bq, bk, bv, QhD, KhD, VtD);

    attn_kernel<<<dim3(16, 32), 256, 0, stream>>>(QhD, KhD, VtD, msk, scores, att);

    o_gemm_kernel<<<dim3(64, 8), 256, 0, stream>>>(att, Wot, bo, out);
}